// Round 1
// baseline (107.793 us; speedup 1.0000x reference)
//
#include <hip/hip_runtime.h>
#include <hip/hip_bf16.h>

#define DIM 256
#define NP 2048
#define NH 8
#define BATCH 2
#define DH 32

typedef __attribute__((ext_vector_type(8))) short bshort8;
typedef __attribute__((ext_vector_type(4))) short bshort4;
typedef __attribute__((ext_vector_type(4))) float f32x4;

#define LOG2E 1.44269504f
// (Dh^-0.5) * log2(e), folded into WT rows 0..255 (W_q) at prep time
#define QSCALE (0.17677669529663687f * LOG2E)

union U16B { uint4 u; bshort8 s8; bshort4 s4x[2]; __hip_bfloat16 h[8]; };
union U8B  { uint2 u; bshort4 s4; __hip_bfloat16 h[4]; };

__device__ __forceinline__ float fexp2(float x) { return __builtin_amdgcn_exp2f(x); }
// pack two fp32 -> two bf16 (truncation) in one v_perm
__device__ __forceinline__ unsigned packbf(float hi, float lo) {
    return __builtin_amdgcn_perm(__float_as_uint(hi), __float_as_uint(lo), 0x07060302u);
}

// LDS tile addressing: 64 rows x 256 elems, XOR-swizzled 16B granules.
// Fragment reads use this; staging now uses global_load_lds with a linear LDS
// dest + inverse-swizzled per-lane GLOBAL source (same involution -> same content).
__device__ __forceinline__ int lds_addr(int row, int colg) {
    return row * 256 + (((colg ^ (row & 7)) & 31) << 3);
}

// async global->LDS, 16B per lane. LDS dest = wave-uniform base + lane*16.
__device__ __forceinline__ void gl16(const void* g, void* l) {
    __builtin_amdgcn_global_load_lds(
        (const __attribute__((address_space(1))) void*)g,
        (__attribute__((address_space(3))) void*)l, 16, 0, 0);
}

// ============ kernel 0: prep — W transpose -> bf16 WT[1024][256]; x -> bf16 ==
// blocks 0-63: WT rows: 0-255 Wq^T*QSCALE, 256-511 Wk^T, 512-767 Wv^T,
//              768-1023 Wproj^T.  blocks 64-127: xb = bf16(x) (RNE, as before).
__global__ __launch_bounds__(256) void prep_kernel(
    const float* __restrict__ Wqk,
    const float* __restrict__ Wv,
    const float* __restrict__ Wproj,
    const float* __restrict__ x,
    __hip_bfloat16* __restrict__ WT,
    __hip_bfloat16* __restrict__ xb) {
    const int t = threadIdx.x;
    const int blk = blockIdx.x;
    if (blk >= 64) {
        // x convert: 64 blocks x 256 thr x 16 iters x 4 floats = 1,048,576
        const int base = (blk - 64) * 256 + t;
#pragma unroll
        for (int i = 0; i < 16; i++) {
            const int idx = base + i * 16384;
            float4 f = *(const float4*)(x + (size_t)idx * 4);
            U8B a;
            a.h[0] = __float2bfloat16(f.x); a.h[1] = __float2bfloat16(f.y);
            a.h[2] = __float2bfloat16(f.z); a.h[3] = __float2bfloat16(f.w);
            *(uint2*)(xb + (size_t)idx * 4) = a.u;
        }
        return;
    }
    __shared__ float ts[64][65];
    const int ct = blk >> 2, k0 = (blk & 3) * 64;
    const int c0 = ct * 64;
    const float* src; int ldw, cs0; float scl = 1.0f;
    if (ct < 8)       { src = Wqk;   ldw = 512; cs0 = c0;      if (ct < 4) scl = QSCALE; }
    else if (ct < 12) { src = Wv;    ldw = 256; cs0 = c0 - 512; }
    else              { src = Wproj; ldw = 256; cs0 = c0 - 768; }
    const int cc = t & 63, tq = t >> 6;
#pragma unroll
    for (int j = 0; j < 16; j++) {
        int kk = tq * 16 + j;
        ts[kk][cc] = src[(size_t)(k0 + kk) * ldw + cs0 + cc];
    }
    __syncthreads();
    const int kk2 = t & 63;
#pragma unroll
    for (int j = 0; j < 16; j++) {
        int cc2 = tq * 16 + j;
        WT[(size_t)(c0 + cc2) * 256 + k0 + kk2] = __float2bfloat16(ts[kk2][cc2] * scl);
    }
}

// ============ kernel 1: QKV projection — global_load_lds staged MFMA GEMM ===
// A = xb[4096x256] bf16, B = WT rows 0..767. grid (64,12), 256 thr / 4 waves.
// q is written TRANSPOSED (qT[(b*256+h*32+d)][token], 8B stores) like vT.
__global__ __launch_bounds__(256) void qkv_mfma(
    const __hip_bfloat16* __restrict__ xb,
    const __hip_bfloat16* __restrict__ WT,
    __hip_bfloat16* __restrict__ qT,
    __hip_bfloat16* __restrict__ k,
    __hip_bfloat16* __restrict__ vT) {
    __shared__ __align__(16) __hip_bfloat16 As[64 * 256];
    __shared__ __align__(16) __hip_bfloat16 Bs[64 * 256];
    const int t = threadIdx.x, lane = t & 63, wvid = t >> 6;
    const int l15 = lane & 15, l4 = lane >> 4;
    const int m0 = blockIdx.x * 64;
    const int nb0 = blockIdx.y * 64;
    const int nc = nb0 + wvid * 16 + l15;

    // stage A and B: each wave covers 2 rows per j; LDS linear, global source
    // granule pre-XOR'd so swizzled fragment reads see the right data.
    const int lrow = lane >> 5, lcg = lane & 31;
#pragma unroll
    for (int j = 0; j < 8; j++) {
        const int r0 = j * 8 + wvid * 2;
        const int row = r0 + lrow;
        const int cgs = (lcg ^ (row & 7)) & 31;
        gl16(xb + (((size_t)(m0 + row)) << 8) + cgs * 8, (char*)As + r0 * 512);
        gl16(WT + (((size_t)(nb0 + row)) << 8) + cgs * 8, (char*)Bs + r0 * 512);
    }
    __syncthreads();

    f32x4 acc[4] = {{0.f,0.f,0.f,0.f},{0.f,0.f,0.f,0.f},{0.f,0.f,0.f,0.f},{0.f,0.f,0.f,0.f}};
#pragma unroll
    for (int kk = 0; kk < 8; kk++) {
        const int colg = kk * 4 + l4;
        U16B bw; bw.u = *(const uint4*)&Bs[lds_addr(wvid * 16 + l15, colg)];
#pragma unroll
        for (int mt = 0; mt < 4; mt++) {
            U16B ax; ax.u = *(const uint4*)&As[lds_addr(mt * 16 + l15, colg)];
            acc[mt] = __builtin_amdgcn_mfma_f32_16x16x32_bf16(ax.s8, bw.s8, acc[mt], 0, 0, 0);
        }
    }

    if (nb0 < 256) {             // qT[(b*256+c)][token], 8B stores (QSCALE in WT)
        const int c = nc;
        const int b = m0 >> 11;
#pragma unroll
        for (int mt = 0; mt < 4; mt++) {
            int tokn = (m0 & (NP - 1)) + mt * 16 + l4 * 4;
            U8B vv;
#pragma unroll
            for (int r = 0; r < 4; r++) vv.h[r] = __float2bfloat16(acc[mt][r]);
            *(uint2*)(qT + (size_t)(b * 256 + c) * NP + tokn) = vv.u;
        }
    } else if (nb0 < 512) {      // k[bh][n][d] (row layout needed by attn staging)
        const int c = nc - 256, h = c >> 5, d = c & 31;
#pragma unroll
        for (int mt = 0; mt < 4; mt++)
#pragma unroll
            for (int r = 0; r < 4; r++) {
                int tok = m0 + mt * 16 + l4 * 4 + r;
                int b = tok >> 11, n = tok & (NP - 1);
                k[((size_t)(b * NH + h) * NP + n) * DH + d] = __float2bfloat16(acc[mt][r]);
            }
    } else {                     // vT[(b*256+c)][token], 8B stores
        const int c = nc - 512;
        const int b = m0 >> 11;
#pragma unroll
        for (int mt = 0; mt < 4; mt++) {
            int tokn = (m0 & (NP - 1)) + mt * 16 + l4 * 4;
            U8B vv;
#pragma unroll
            for (int r = 0; r < 4; r++) vv.h[r] = __float2bfloat16(acc[mt][r]);
            *(uint2*)(vT + (size_t)(b * 256 + c) * NP + tokn) = vv.u;
        }
    }
}

// ============ kernel 2: attention — LDS-staged K/V, register P, split-K =====
// grid 512 = bh(16) x qb(32 of 64q). 512 thr / 8 waves: qt = wv&3, kh = wv>>2.
// Vt columns permuted (c' = l4*16 + kt*4 + j) so V fragments read as b128.
__global__ __launch_bounds__(512, 4) void attn_kernel(
    const __hip_bfloat16* __restrict__ qg,   // qT[bh*32+d][n]
    const __hip_bfloat16* __restrict__ kg,
    const __hip_bfloat16* __restrict__ vTg,
    const float* __restrict__ Wpos,
    const float* __restrict__ bpos,
    const float* __restrict__ gating,
    __hip_bfloat16* __restrict__ ao) {
    __shared__ __align__(16) __hip_bfloat16 Kt[2][2][64][40];  // [kh][buf][key][dh pad40]
    __shared__ __align__(16) __hip_bfloat16 Vt[2][2][32][72];  // [kh][buf][d][key perm pad72]
    __shared__ float cmb[4][2][32][16];   // [qt][type][d][q] upper-half partial O
    __shared__ float cls[4][2][16];       // [qt][type][q]    upper-half partial sums

    const int t = threadIdx.x;
    const int lane = t & 63, wvid = t >> 6;
    const int l15 = lane & 15, l4 = lane >> 4;
    const int qt = wvid & 3, kh = wvid >> 2;
    const int bh = blockIdx.x >> 5, qb = blockIdx.x & 31;
    const int h = bh & (NH - 1), b = bh >> 3;
    const int q0 = qb * 64 + qt * 16;
    const int myq = q0 + l15;

    const int st_ = t & 255;
    const int kstart = kh * 1024;
    const __hip_bfloat16* kptr = kg + (size_t)bh * NP * DH + (size_t)(kstart + (st_ >> 2)) * DH + (st_ & 3) * 8;
    const __hip_bfloat16* vptr = vTg + ((size_t)bh * DH + (st_ >> 3)) * NP + kstart + (st_ & 7) * 8;

    // permuted V staging addresses (c = s*8+e -> c' = l4(c)*16 + kt(c)*4 + j(c))
    const int vd = st_ >> 3, vs = st_ & 7;
    const int vc0 = ((2 * vs) & 3) * 16 + (vs >> 1) * 4;
    const int vc1 = ((2 * vs + 1) & 3) * 16 + (vs >> 1) * 4;

    uint4 kreg = *(const uint4*)kptr;
    uint4 vreg = *(const uint4*)vptr;
    *(uint4*)&Kt[kh][0][st_ >> 2][(st_ & 3) * 8] = kreg;
    *(uint2*)&Vt[kh][0][vd][vc0] = make_uint2(vreg.x, vreg.y);
    *(uint2*)&Vt[kh][0][vd][vc1] = make_uint2(vreg.z, vreg.w);

    const float w0 = Wpos[h] * LOG2E;
    const float w1 = Wpos[NH + h] * LOG2E;
    const float g = 1.0f / (1.0f + __expf(-gating[h]));
    const float nf = (float)myq;
    const float pmax = fmaxf(0.f, fmaxf((w0 + w1) * nf, (w1 - w0) * (2047.0f - nf)));
    const float npmax = -pmax;
    const float rA = fexp2(-(w0 + w1));
    const float rB = fexp2(w1 - w0);

    U16B qv;
#pragma unroll
    for (int j = 0; j < 8; j++)
        qv.h[j] = qg[((size_t)bh * DH + l4 * 8 + j) * NP + myq];

    __syncthreads();

    f32x4 os0 = {0.f,0.f,0.f,0.f}, os1 = {0.f,0.f,0.f,0.f};
    f32x4 op0 = {0.f,0.f,0.f,0.f}, op1 = {0.f,0.f,0.f,0.f};
    float ls = 0.f, lp = 0.f;

    for (int it = 0; it < 16; ++it) {
        const int cur = it & 1, nxt = cur ^ 1;

        if (it < 15) {
            kreg = *(const uint4*)(kptr + (size_t)(it + 1) * 64 * DH);
            vreg = *(const uint4*)(vptr + (it + 1) * 64);
        }

        f32x4 st4[4];
#pragma unroll
        for (int kt = 0; kt < 4; kt++) {
            U16B kf; kf.u = *(const uint4*)&Kt[kh][cur][kt * 16 + l15][l4 * 8];
            st4[kt] = __builtin_amdgcn_mfma_f32_16x16x32_bf16(
                kf.s8, qv.s8, (f32x4){0.f,0.f,0.f,0.f}, 0, 0, 0);
        }

        // V fragments: 4x b128 (was 8x b64) thanks to column permutation
        U16B va0, va1, vb0, vb1;
        {
            const __hip_bfloat16* v0 = &Vt[kh][cur][l15][l4 * 16];
            const __hip_bfloat16* v1 = &Vt[kh][cur][16 + l15][l4 * 16];
            va0.u = *(const uint4*)v0;
            va1.u = *(const uint4*)(v0 + 8);
            vb0.u = *(const uint4*)v1;
            vb1.u = *(const uint4*)(v1 + 8);
        }

        const int kb0 = kstart + it * 64;
#pragma unroll
        for (int kt = 0; kt < 4; kt++) {
            const bshort4 fa = (kt < 2) ? va0.s4x[kt & 1] : va1.s4x[kt & 1];
            const bshort4 fb = (kt < 2) ? vb0.s4x[kt & 1] : vb1.s4x[kt & 1];
            float es0 = fexp2(st4[kt][0]), es1 = fexp2(st4[kt][1]);
            float es2 = fexp2(st4[kt][2]), es3 = fexp2(st4[kt][3]);
            ls += (es0 + es1) + (es2 + es3);
            const float d0 = nf - (float)(kb0 + kt * 16 + l4 * 4);
            float ep0 = fexp2(fmaf(w1, fabsf(d0), fmaf(w0, d0, npmax)));
            float ep1 = ep0 * ((d0 >= 1.f) ? rA : rB);
            float ep2 = ep1 * ((d0 >= 2.f) ? rA : rB);
            float ep3 = ep2 * ((d0 >= 3.f) ? rA : rB);
            lp += (ep0 + ep1) + (ep2 + ep3);
            U8B pc, pp;
            pc.u.x = packbf(es1, es0); pc.u.y = packbf(es3, es2);
            pp.u.x = packbf(ep1, ep0); pp.u.y = packbf(ep3, ep2);
            os0 = __builtin_amdgcn_mfma_f32_16x16x16bf16_1k(fa, pc.s4, os0, 0, 0, 0);
            os1 = __builtin_amdgcn_mfma_f32_16x16x16bf16_1k(fb, pc.s4, os1, 0, 0, 0);
            op0 = __builtin_amdgcn_mfma_f32_16x16x16bf16_1k(fa, pp.s4, op0, 0, 0, 0);
            op1 = __builtin_amdgcn_mfma_f32_16x16x16bf16_1k(fb, pp.s4, op1, 0, 0, 0);
        }

        if (it < 15) {
            *(uint4*)&Kt[kh][nxt][st_ >> 2][(st_ & 3) * 8] = kreg;
            *(uint2*)&Vt[kh][nxt][vd][vc0] = make_uint2(vreg.x, vreg.y);
            *(uint2*)&Vt[kh][nxt][vd][vc1] = make_uint2(vreg.z, vreg.w);
        }
        __syncthreads();
    }

    ls += __shfl_xor(ls, 16, 64); ls += __shfl_xor(ls, 32, 64);
    lp += __shfl_xor(lp, 16, 64); lp += __shfl_xor(lp, 32, 64);

    if (kh == 1) {
#pragma unroll
        for (int r = 0; r < 4; r++) {
            cmb[qt][0][l4 * 4 + r][l15]      = os0[r];
            cmb[qt][0][16 + l4 * 4 + r][l15] = os1[r];
            cmb[qt][1][l4 * 4 + r][l15]      = op0[r];
            cmb[qt][1][16 + l4 * 4 + r][l15] = op1[r];
        }
        if (l4 == 0) { cls[qt][0][l15] = ls; cls[qt][1][l15] = lp; }
    }
    __syncthreads();
    if (kh == 0) {
        ls += cls[qt][0][l15]; lp += cls[qt][1][l15];
        const float cs = (1.0f - g) / ls;
        const float cp = g / lp;
        const size_t orow = ((size_t)b * NP + myq) * DIM + h * DH;
        U8B o0, o1;
#pragma unroll
        for (int r = 0; r < 4; r++) {
            o0.h[r] = __float2bfloat16(cs * (os0[r] + cmb[qt][0][l4 * 4 + r][l15]) +
                                       cp * (op0[r] + cmb[qt][1][l4 * 4 + r][l15]));
            o1.h[r] = __float2bfloat16(cs * (os1[r] + cmb[qt][0][16 + l4 * 4 + r][l15]) +
                                       cp * (op1[r] + cmb[qt][1][16 + l4 * 4 + r][l15]));
        }
        *(uint2*)(ao + orow + l4 * 4)      = o0.u;
        *(uint2*)(ao + orow + 16 + l4 * 4) = o1.u;
    }
}

// ============ kernel 3: output projection — global_load_lds staged GEMM =====
// A = ao[4096x256] bf16, B = WT rows 768..1023, +bias, out fp32. grid (64,4).
__global__ __launch_bounds__(256) void proj_mfma(
    const __hip_bfloat16* __restrict__ ao,
    const __hip_bfloat16* __restrict__ WT,
    const float* __restrict__ bias,
    float* __restrict__ out) {
    __shared__ __align__(16) __hip_bfloat16 As[64 * 256];
    __shared__ __align__(16) __hip_bfloat16 Bs[64 * 256];
    const int t = threadIdx.x, lane = t & 63, wvid = t >> 6;
    const int l15 = lane & 15, l4 = lane >> 4;
    const int m0 = blockIdx.x * 64;
    const int nb0 = blockIdx.y * 64;
    const int nc = nb0 + wvid * 16 + l15;

    const int lrow = lane >> 5, lcg = lane & 31;
#pragma unroll
    for (int j = 0; j < 8; j++) {
        const int r0 = j * 8 + wvid * 2;
        const int row = r0 + lrow;
        const int cgs = (lcg ^ (row & 7)) & 31;
        gl16(ao + (((size_t)(m0 + row)) << 8) + cgs * 8, (char*)As + r0 * 512);
        gl16(WT + (((size_t)(768 + nb0 + row)) << 8) + cgs * 8, (char*)Bs + r0 * 512);
    }
    __syncthreads();

    f32x4 acc[4] = {{0.f,0.f,0.f,0.f},{0.f,0.f,0.f,0.f},{0.f,0.f,0.f,0.f},{0.f,0.f,0.f,0.f}};
#pragma unroll
    for (int kk = 0; kk < 8; kk++) {
        const int colg = kk * 4 + l4;
        U16B bw; bw.u = *(const uint4*)&Bs[lds_addr(wvid * 16 + l15, colg)];
#pragma unroll
        for (int mt = 0; mt < 4; mt++) {
            U16B ax; ax.u = *(const uint4*)&As[lds_addr(mt * 16 + l15, colg)];
            acc[mt] = __builtin_amdgcn_mfma_f32_16x16x32_bf16(ax.s8, bw.s8, acc[mt], 0, 0, 0);
        }
    }

    const float bb = bias[nc];
#pragma unroll
    for (int mt = 0; mt < 4; mt++)
#pragma unroll
        for (int r = 0; r < 4; r++) {
            int tok = m0 + mt * 16 + l4 * 4 + r;
            out[(size_t)tok * 256 + nc] = acc[mt][r] + bb;
        }
}

extern "C" void kernel_launch(void* const* d_in, const int* in_sizes, int n_in,
                              void* d_out, int out_size, void* d_ws, size_t ws_size,
                              hipStream_t stream) {
    const float* x      = (const float*)d_in[0];
    const float* Wqk    = (const float*)d_in[1];
    const float* Wv     = (const float*)d_in[2];
    const float* Wproj  = (const float*)d_in[3];
    const float* bproj  = (const float*)d_in[4];
    const float* Wpos   = (const float*)d_in[5];
    const float* bpos   = (const float*)d_in[6];
    const float* gating = (const float*)d_in[7];
    float* out = (float*)d_out;

    const size_t nElem = (size_t)BATCH * NP * DIM;  // 1,048,576
    char* w = (char*)d_ws;
    __hip_bfloat16* WT = (__hip_bfloat16*)w;        // 512KB
    __hip_bfloat16* qT = WT + 262144;
    __hip_bfloat16* k  = qT + nElem;
    __hip_bfloat16* vT = k + nElem;
    __hip_bfloat16* ao = vT + nElem;
    __hip_bfloat16* xb = ao + nElem;                // total 10.5MB

    prep_kernel<<<128, 256, 0, stream>>>(Wqk, Wv, Wproj, x, WT, xb);
    qkv_mfma<<<dim3(64, 12), 256, 0, stream>>>(xb, WT, qT, k, vT);
    attn_kernel<<<BATCH * NH * (NP / 64), 512, 0, stream>>>(qT, k, vT, Wpos, bpos, gating, ao);
    proj_mfma<<<dim3(64, 4), 256, 0, stream>>>(ao, WT, bproj, out);
}